// Round 1
// baseline (1502.882 us; speedup 1.0000x reference)
//
#include <hip/hip_runtime.h>
#include <math.h>

// Shapes (fixed by the problem)
#define BB 16
#define C  512
#define P  4
#define NN 1024
#define BP (BB*P)     // 64
#define PN (P*NN)     // 4096 : stride between channels c for fixed (b,p)

// k_vo tiling
#define BN 64         // columns (n) per workgroup
#define KT 16         // K-tile
#define ACT_LD 68     // padded leading dim of act tile  (68*4B = 272B, 16B-aligned rows)
#define WT_LD  260    // padded leading dim of transposed w tile (260*4B = 1040B, 16B-aligned)
#define XT_LD  68

// ---------------------------------------------------------------------------
// Kernel 1: query[bp][n] = b_q + sum_c w_qkv[0][c] * x[b,c,p,n]
// grid: BP*4 blocks of 256 threads (each block: one (b,p), 256 n's)
// ---------------------------------------------------------------------------
__global__ __launch_bounds__(256) void k_query(const float* __restrict__ x,
                                               const float* __restrict__ w_qkv,
                                               const float* __restrict__ b_qkv,
                                               float* __restrict__ query) {
    __shared__ float wq[C];
    const int bp  = blockIdx.x >> 2;
    const int q4  = blockIdx.x & 3;
    const int b   = bp >> 2, p = bp & 3;
    const int tid = threadIdx.x;
    for (int i = tid; i < C; i += 256) wq[i] = w_qkv[i];
    __syncthreads();
    const int n = q4 * 256 + tid;
    const float* xb = x + (size_t)b * C * PN + (size_t)p * NN + n;
    float a0 = 0.f, a1 = 0.f, a2 = 0.f, a3 = 0.f;
    #pragma unroll 4
    for (int c = 0; c < C; c += 4) {
        a0 = fmaf(xb[(size_t)(c + 0) * PN], wq[c + 0], a0);
        a1 = fmaf(xb[(size_t)(c + 1) * PN], wq[c + 1], a1);
        a2 = fmaf(xb[(size_t)(c + 2) * PN], wq[c + 2], a2);
        a3 = fmaf(xb[(size_t)(c + 3) * PN], wq[c + 3], a3);
    }
    query[bp * NN + n] = b_qkv[0] + ((a0 + a1) + (a2 + a3));
}

// ---------------------------------------------------------------------------
// Kernel 2: scores = softmax(query) over N, per bp.  grid: BP blocks
// ---------------------------------------------------------------------------
__global__ __launch_bounds__(256) void k_softmax(const float* __restrict__ query,
                                                 float* __restrict__ scores) {
    __shared__ float red[256];
    const int bp = blockIdx.x, tid = threadIdx.x;
    const float* q = query + bp * NN;
    float v[4];
    float m = -INFINITY;
    #pragma unroll
    for (int j = 0; j < 4; ++j) { v[j] = q[tid + 256 * j]; m = fmaxf(m, v[j]); }
    red[tid] = m; __syncthreads();
    for (int s = 128; s > 0; s >>= 1) {
        if (tid < s) red[tid] = fmaxf(red[tid], red[tid + s]);
        __syncthreads();
    }
    m = red[0]; __syncthreads();
    float sum = 0.f;
    #pragma unroll
    for (int j = 0; j < 4; ++j) { v[j] = expf(v[j] - m); sum += v[j]; }
    red[tid] = sum; __syncthreads();
    for (int s = 128; s > 0; s >>= 1) {
        if (tid < s) red[tid] += red[tid + s];
        __syncthreads();
    }
    const float inv = 1.0f / red[0];
    #pragma unroll
    for (int j = 0; j < 4; ++j) scores[bp * NN + tid + 256 * j] = v[j] * inv;
}

// ---------------------------------------------------------------------------
// Kernel 3: xs[bp][c] = sum_n x[b,c,p,n] * scores[bp][n]
// grid: BP*8 blocks (64 channels each), 256 threads (4 waves x 16 rows)
// ---------------------------------------------------------------------------
__global__ __launch_bounds__(256) void k_xs(const float* __restrict__ x,
                                            const float* __restrict__ scores,
                                            float* __restrict__ xs) {
    __shared__ float sc[NN];
    const int bp = blockIdx.x >> 3, cc = blockIdx.x & 7;
    const int b = bp >> 2, p = bp & 3;
    const int tid = threadIdx.x;
    for (int i = tid; i < NN; i += 256) sc[i] = scores[bp * NN + i];
    __syncthreads();
    const int wave = tid >> 6, lane = tid & 63;
    const float* xb = x + (size_t)b * C * PN + (size_t)p * NN;
    for (int k = 0; k < 16; ++k) {
        const int c = cc * 64 + wave * 16 + k;
        const float* row = xb + (size_t)c * PN;
        float acc = 0.f;
        #pragma unroll
        for (int j = 0; j < 16; ++j) acc = fmaf(row[lane + 64 * j], sc[lane + 64 * j], acc);
        #pragma unroll
        for (int off = 32; off > 0; off >>= 1) acc += __shfl_down(acc, off);
        if (lane == 0) xs[bp * C + c] = acc;
    }
}

// ---------------------------------------------------------------------------
// Kernel 4: cv[bp][o] = b_qkv[1+o] + sum_c w_qkv[1+o][c] * xs[bp][c]
// grid: BP blocks, wave-per-output-row reduction
// ---------------------------------------------------------------------------
__global__ __launch_bounds__(256) void k_cv(const float* __restrict__ xs,
                                            const float* __restrict__ w_qkv,
                                            const float* __restrict__ b_qkv,
                                            float* __restrict__ cv) {
    __shared__ float xsl[C];
    const int bp = blockIdx.x, tid = threadIdx.x;
    for (int i = tid; i < C; i += 256) xsl[i] = xs[bp * C + i];
    __syncthreads();
    const int wave = tid >> 6, lane = tid & 63;
    for (int o = wave; o < C; o += 4) {
        const float* wr = w_qkv + (size_t)(1 + o) * C;
        float acc = 0.f;
        #pragma unroll
        for (int j = 0; j < 8; ++j) acc = fmaf(wr[lane + 64 * j], xsl[lane + 64 * j], acc);
        #pragma unroll
        for (int off = 32; off > 0; off >>= 1) acc += __shfl_down(acc, off);
        if (lane == 0) cv[bp * C + o] = acc + b_qkv[1 + o];
    }
}

// ---------------------------------------------------------------------------
// Kernel 5 (the heavy one): per (bp, 64-column tile):
//   act[c][nn] = relu(sum_c' w_v[c][c']*x[c'][nn] + b_v[c]) * cv[c]   (kept in LDS)
//   out[o][nn] = sum_c w_out[o][c]*act[c][nn] + b_out[o]
// 256 threads; thread tile 8x8; two 256-row M-chunks per phase.
// LDS: act[512][68] + wt[16][260] + xt[16][68] = 160,256 B (fits 160 KiB).
// ---------------------------------------------------------------------------
__global__ __launch_bounds__(256, 1) void k_vo(const float* __restrict__ x,
                                               const float* __restrict__ w_qkv,
                                               const float* __restrict__ b_qkv,
                                               const float* __restrict__ w_out,
                                               const float* __restrict__ b_out,
                                               const float* __restrict__ cv,
                                               float* __restrict__ out) {
    extern __shared__ float lds[];
    float* act = lds;                       // [C][ACT_LD]
    float* wt  = act + C * ACT_LD;          // [KT][WT_LD]  (transposed: wt[kk][r])
    float* xt  = wt + KT * WT_LD;           // [KT][XT_LD]

    const int nt = blockIdx.x;              // 0..15
    const int bp = blockIdx.y;              // 0..63
    const int b = bp >> 2, p = bp & 3;
    const int n0 = nt * BN;
    const int tid = threadIdx.x;
    const int ty = tid >> 3;                // 0..31 (row group)
    const int tx = tid & 7;                 // 0..7  (col group)
    const float* xb  = x + (size_t)b * C * PN + (size_t)p * NN + n0;
    const float* cvb = cv + bp * C;

    // ------------------ Phase V: build act in LDS ------------------
    for (int mc = 0; mc < 2; ++mc) {
        const int r0 = mc * 256;
        float acc[8][8];
        #pragma unroll
        for (int i = 0; i < 8; ++i)
            #pragma unroll
            for (int j = 0; j < 8; ++j) acc[i][j] = 0.f;

        for (int kt = 0; kt < C / KT; ++kt) {
            const int k0 = kt * KT;
            // stage w_v tile transposed: wt[kk][r], r = tid
            {
                const float* wrow = w_qkv + (size_t)(1 + C + r0 + tid) * C + k0;
                const float4 t0 = *reinterpret_cast<const float4*>(wrow + 0);
                const float4 t1 = *reinterpret_cast<const float4*>(wrow + 4);
                const float4 t2 = *reinterpret_cast<const float4*>(wrow + 8);
                const float4 t3 = *reinterpret_cast<const float4*>(wrow + 12);
                const float tmp[16] = {t0.x,t0.y,t0.z,t0.w,t1.x,t1.y,t1.z,t1.w,
                                       t2.x,t2.y,t2.z,t2.w,t3.x,t3.y,t3.z,t3.w};
                #pragma unroll
                for (int kk = 0; kk < KT; ++kk) wt[kk * WT_LD + tid] = tmp[kk];
            }
            // stage x tile: xt[kk][nn]
            {
                const int kk = tid >> 4, nn = (tid & 15) * 4;
                *reinterpret_cast<float4*>(&xt[kk * XT_LD + nn]) =
                    *reinterpret_cast<const float4*>(xb + (size_t)(k0 + kk) * PN + nn);
            }
            __syncthreads();
            #pragma unroll
            for (int kk = 0; kk < KT; ++kk) {
                const float4 a0 = *reinterpret_cast<const float4*>(&wt[kk * WT_LD + ty * 8]);
                const float4 a1 = *reinterpret_cast<const float4*>(&wt[kk * WT_LD + ty * 8 + 4]);
                const float4 b0 = *reinterpret_cast<const float4*>(&xt[kk * XT_LD + tx * 8]);
                const float4 b1 = *reinterpret_cast<const float4*>(&xt[kk * XT_LD + tx * 8 + 4]);
                const float av[8] = {a0.x,a0.y,a0.z,a0.w,a1.x,a1.y,a1.z,a1.w};
                const float bv[8] = {b0.x,b0.y,b0.z,b0.w,b1.x,b1.y,b1.z,b1.w};
                #pragma unroll
                for (int i = 0; i < 8; ++i)
                    #pragma unroll
                    for (int j = 0; j < 8; ++j)
                        acc[i][j] = fmaf(av[i], bv[j], acc[i][j]);
            }
            __syncthreads();
        }
        // finalize: relu(value + b_v) * cv -> act
        #pragma unroll
        for (int i = 0; i < 8; ++i) {
            const int r = r0 + ty * 8 + i;
            const float bb = b_qkv[1 + C + r];
            const float cc = cvb[r];
            float4 o0, o1;
            o0.x = fmaxf(acc[i][0] + bb, 0.f) * cc;
            o0.y = fmaxf(acc[i][1] + bb, 0.f) * cc;
            o0.z = fmaxf(acc[i][2] + bb, 0.f) * cc;
            o0.w = fmaxf(acc[i][3] + bb, 0.f) * cc;
            o1.x = fmaxf(acc[i][4] + bb, 0.f) * cc;
            o1.y = fmaxf(acc[i][5] + bb, 0.f) * cc;
            o1.z = fmaxf(acc[i][6] + bb, 0.f) * cc;
            o1.w = fmaxf(acc[i][7] + bb, 0.f) * cc;
            *reinterpret_cast<float4*>(&act[r * ACT_LD + tx * 8])     = o0;
            *reinterpret_cast<float4*>(&act[r * ACT_LD + tx * 8 + 4]) = o1;
        }
    }
    __syncthreads();

    // ------------------ Phase O: out = w_out * act + b_out ------------------
    for (int mc = 0; mc < 2; ++mc) {
        const int o0 = mc * 256;
        float acc[8][8];
        #pragma unroll
        for (int i = 0; i < 8; ++i)
            #pragma unroll
            for (int j = 0; j < 8; ++j) acc[i][j] = 0.f;

        for (int kt = 0; kt < C / KT; ++kt) {
            const int k0 = kt * KT;
            {
                const float* wrow = w_out + (size_t)(o0 + tid) * C + k0;
                const float4 t0 = *reinterpret_cast<const float4*>(wrow + 0);
                const float4 t1 = *reinterpret_cast<const float4*>(wrow + 4);
                const float4 t2 = *reinterpret_cast<const float4*>(wrow + 8);
                const float4 t3 = *reinterpret_cast<const float4*>(wrow + 12);
                const float tmp[16] = {t0.x,t0.y,t0.z,t0.w,t1.x,t1.y,t1.z,t1.w,
                                       t2.x,t2.y,t2.z,t2.w,t3.x,t3.y,t3.z,t3.w};
                #pragma unroll
                for (int kk = 0; kk < KT; ++kk) wt[kk * WT_LD + tid] = tmp[kk];
            }
            __syncthreads();
            #pragma unroll
            for (int kk = 0; kk < KT; ++kk) {
                const float4 a0 = *reinterpret_cast<const float4*>(&wt[kk * WT_LD + ty * 8]);
                const float4 a1 = *reinterpret_cast<const float4*>(&wt[kk * WT_LD + ty * 8 + 4]);
                const float4 b0 = *reinterpret_cast<const float4*>(&act[(k0 + kk) * ACT_LD + tx * 8]);
                const float4 b1 = *reinterpret_cast<const float4*>(&act[(k0 + kk) * ACT_LD + tx * 8 + 4]);
                const float av[8] = {a0.x,a0.y,a0.z,a0.w,a1.x,a1.y,a1.z,a1.w};
                const float bv[8] = {b0.x,b0.y,b0.z,b0.w,b1.x,b1.y,b1.z,b1.w};
                #pragma unroll
                for (int i = 0; i < 8; ++i)
                    #pragma unroll
                    for (int j = 0; j < 8; ++j)
                        acc[i][j] = fmaf(av[i], bv[j], acc[i][j]);
            }
            __syncthreads();
        }
        #pragma unroll
        for (int i = 0; i < 8; ++i) {
            const int o = o0 + ty * 8 + i;
            const float bo = b_out[o];
            float* orow = out + ((size_t)(b * C + o) * P + p) * NN + n0;
            float4 o0v, o1v;
            o0v.x = acc[i][0] + bo; o0v.y = acc[i][1] + bo;
            o0v.z = acc[i][2] + bo; o0v.w = acc[i][3] + bo;
            o1v.x = acc[i][4] + bo; o1v.y = acc[i][5] + bo;
            o1v.z = acc[i][6] + bo; o1v.w = acc[i][7] + bo;
            *reinterpret_cast<float4*>(&orow[tx * 8])     = o0v;
            *reinterpret_cast<float4*>(&orow[tx * 8 + 4]) = o1v;
        }
    }
}

// ---------------------------------------------------------------------------
extern "C" void kernel_launch(void* const* d_in, const int* in_sizes, int n_in,
                              void* d_out, int out_size, void* d_ws, size_t ws_size,
                              hipStream_t stream) {
    const float* x     = (const float*)d_in[0];
    const float* w_qkv = (const float*)d_in[1];
    const float* b_qkv = (const float*)d_in[2];
    const float* w_out = (const float*)d_in[3];
    const float* b_out = (const float*)d_in[4];
    float* out = (float*)d_out;

    float* query  = (float*)d_ws;            // BP*N
    float* scores = query + BP * NN;         // BP*N
    float* xs     = scores + BP * NN;        // BP*C
    float* cv     = xs + BP * C;             // BP*C   (total ~768 KB of ws)

    k_query  <<<dim3(BP * 4), 256, 0, stream>>>(x, w_qkv, b_qkv, query);
    k_softmax<<<dim3(BP),     256, 0, stream>>>(query, scores);
    k_xs     <<<dim3(BP * 8), 256, 0, stream>>>(x, scores, xs);
    k_cv     <<<dim3(BP),     256, 0, stream>>>(xs, w_qkv, b_qkv, cv);

    const size_t ldsbytes = (size_t)(C * ACT_LD + KT * WT_LD + KT * XT_LD) * sizeof(float);
    k_vo<<<dim3(16, BP), 256, ldsbytes, stream>>>(x, w_qkv, b_qkv, w_out, b_out, cv, out);
}

// Round 2
// 649.104 us; speedup vs baseline: 2.3153x; 2.3153x over previous
//
#include <hip/hip_runtime.h>
#include <math.h>

// Shapes (fixed by the problem)
#define BB 16
#define C  512
#define P  4
#define NN 1024
#define BP (BB*P)     // 64
#define PN (P*NN)     // 4096 : stride between channels c for fixed (b,p)

typedef short bf16x8 __attribute__((ext_vector_type(8)));
typedef float f32x4  __attribute__((ext_vector_type(4)));

__device__ __forceinline__ unsigned short bf16rne(float f) {
    unsigned u = __float_as_uint(f);
    u += 0x7FFFu + ((u >> 16) & 1u);
    return (unsigned short)(u >> 16);
}
__device__ __forceinline__ float bf16tof(unsigned short h) {
    return __uint_as_float(((unsigned)h) << 16);
}

// ---------------------------------------------------------------------------
// Kernel 0: split weights into bf16 hi/lo (done every launch; ws is re-poisoned)
// wv = value weights (w_qkv rows 1+C .. 2C), wo = w_out. 512 blocks x 256.
// ---------------------------------------------------------------------------
__global__ __launch_bounds__(256) void k_split(const float* __restrict__ w_qkv,
                                               const float* __restrict__ w_out,
                                               unsigned short* __restrict__ wv_hi,
                                               unsigned short* __restrict__ wv_lo,
                                               unsigned short* __restrict__ wo_hi,
                                               unsigned short* __restrict__ wo_lo) {
    const int i = blockIdx.x * 256 + threadIdx.x;   // 0..131071
    const int e = i * 4;
    const float* src; unsigned short *dh, *dl; int off;
    if (e < C * C) { src = w_qkv + (size_t)(1 + C) * C; dh = wv_hi; dl = wv_lo; off = e; }
    else           { src = w_out;                       dh = wo_hi; dl = wo_lo; off = e - C * C; }
    const float4 v = *reinterpret_cast<const float4*>(src + off);
    const float vv[4] = {v.x, v.y, v.z, v.w};
    unsigned short h[4], l[4];
    #pragma unroll
    for (int j = 0; j < 4; ++j) {
        h[j] = bf16rne(vv[j]);
        l[j] = bf16rne(vv[j] - bf16tof(h[j]));
    }
    uint2 ph, pl;
    ph.x = (unsigned)h[0] | ((unsigned)h[1] << 16);
    ph.y = (unsigned)h[2] | ((unsigned)h[3] << 16);
    pl.x = (unsigned)l[0] | ((unsigned)l[1] << 16);
    pl.y = (unsigned)l[2] | ((unsigned)l[3] << 16);
    *reinterpret_cast<uint2*>(dh + off) = ph;
    *reinterpret_cast<uint2*>(dl + off) = pl;
}

// ---------------------------------------------------------------------------
// Kernel 1: query[bp][n] = b_q + sum_c w_qkv[0][c] * x[b,c,p,n]
// ---------------------------------------------------------------------------
__global__ __launch_bounds__(256) void k_query(const float* __restrict__ x,
                                               const float* __restrict__ w_qkv,
                                               const float* __restrict__ b_qkv,
                                               float* __restrict__ query) {
    __shared__ float wq[C];
    const int bp  = blockIdx.x >> 2;
    const int q4  = blockIdx.x & 3;
    const int b   = bp >> 2, p = bp & 3;
    const int tid = threadIdx.x;
    for (int i = tid; i < C; i += 256) wq[i] = w_qkv[i];
    __syncthreads();
    const int n = q4 * 256 + tid;
    const float* xb = x + (size_t)b * C * PN + (size_t)p * NN + n;
    float a0 = 0.f, a1 = 0.f, a2 = 0.f, a3 = 0.f;
    #pragma unroll 4
    for (int c = 0; c < C; c += 4) {
        a0 = fmaf(xb[(size_t)(c + 0) * PN], wq[c + 0], a0);
        a1 = fmaf(xb[(size_t)(c + 1) * PN], wq[c + 1], a1);
        a2 = fmaf(xb[(size_t)(c + 2) * PN], wq[c + 2], a2);
        a3 = fmaf(xb[(size_t)(c + 3) * PN], wq[c + 3], a3);
    }
    query[bp * NN + n] = b_qkv[0] + ((a0 + a1) + (a2 + a3));
}

// ---------------------------------------------------------------------------
// Kernel 2: scores = softmax(query) over N, per bp.  grid: BP blocks
// ---------------------------------------------------------------------------
__global__ __launch_bounds__(256) void k_softmax(const float* __restrict__ query,
                                                 float* __restrict__ scores) {
    __shared__ float red[256];
    const int bp = blockIdx.x, tid = threadIdx.x;
    const float* q = query + bp * NN;
    float v[4];
    float m = -INFINITY;
    #pragma unroll
    for (int j = 0; j < 4; ++j) { v[j] = q[tid + 256 * j]; m = fmaxf(m, v[j]); }
    red[tid] = m; __syncthreads();
    for (int s = 128; s > 0; s >>= 1) {
        if (tid < s) red[tid] = fmaxf(red[tid], red[tid + s]);
        __syncthreads();
    }
    m = red[0]; __syncthreads();
    float sum = 0.f;
    #pragma unroll
    for (int j = 0; j < 4; ++j) { v[j] = expf(v[j] - m); sum += v[j]; }
    red[tid] = sum; __syncthreads();
    for (int s = 128; s > 0; s >>= 1) {
        if (tid < s) red[tid] += red[tid + s];
        __syncthreads();
    }
    const float inv = 1.0f / red[0];
    #pragma unroll
    for (int j = 0; j < 4; ++j) scores[bp * NN + tid + 256 * j] = v[j] * inv;
}

// ---------------------------------------------------------------------------
// Kernel 3: xs[bp][c] = sum_n x[b,c,p,n] * scores[bp][n]
// ---------------------------------------------------------------------------
__global__ __launch_bounds__(256) void k_xs(const float* __restrict__ x,
                                            const float* __restrict__ scores,
                                            float* __restrict__ xs) {
    __shared__ float sc[NN];
    const int bp = blockIdx.x >> 3, cc = blockIdx.x & 7;
    const int b = bp >> 2, p = bp & 3;
    const int tid = threadIdx.x;
    for (int i = tid; i < NN; i += 256) sc[i] = scores[bp * NN + i];
    __syncthreads();
    const int wave = tid >> 6, lane = tid & 63;
    const float* xb = x + (size_t)b * C * PN + (size_t)p * NN;
    for (int k = 0; k < 16; ++k) {
        const int c = cc * 64 + wave * 16 + k;
        const float* row = xb + (size_t)c * PN;
        float acc = 0.f;
        #pragma unroll
        for (int j = 0; j < 16; ++j) acc = fmaf(row[lane + 64 * j], sc[lane + 64 * j], acc);
        #pragma unroll
        for (int off = 32; off > 0; off >>= 1) acc += __shfl_down(acc, off);
        if (lane == 0) xs[bp * C + c] = acc;
    }
}

// ---------------------------------------------------------------------------
// Kernel 4: cv[bp][o] = b_qkv[1+o] + sum_c w_qkv[1+o][c] * xs[bp][c]
// ---------------------------------------------------------------------------
__global__ __launch_bounds__(256) void k_cv(const float* __restrict__ xs,
                                            const float* __restrict__ w_qkv,
                                            const float* __restrict__ b_qkv,
                                            float* __restrict__ cv) {
    __shared__ float xsl[C];
    const int bp = blockIdx.x, tid = threadIdx.x;
    for (int i = tid; i < C; i += 256) xsl[i] = xs[bp * C + i];
    __syncthreads();
    const int wave = tid >> 6, lane = tid & 63;
    for (int o = wave; o < C; o += 4) {
        const float* wr = w_qkv + (size_t)(1 + o) * C;
        float acc = 0.f;
        #pragma unroll
        for (int j = 0; j < 8; ++j) acc = fmaf(wr[lane + 64 * j], xsl[lane + 64 * j], acc);
        #pragma unroll
        for (int off = 32; off > 0; off >>= 1) acc += __shfl_down(acc, off);
        if (lane == 0) cv[bp * C + o] = acc + b_qkv[1 + o];
    }
}

// ---------------------------------------------------------------------------
// Kernel 5: MFMA bf16x3 fused value-GEMM -> relu*cv -> out-GEMM.
// Block = (n-tile of 64, bp). 512 threads = 8 waves, each wave owns 64 M-rows.
// LDS: act hi/lo [64 cols][520 c] bf16 (133 KB) + xt hi/lo [64][40] (10 KB)
//      + scratch [32][68] f32 (8.7 KB) = 152,064 B -> 1 block/CU, 2 waves/SIMD.
// MFMA frag maps (16x16x32): A[row=l&15][k=(l>>4)*8+j], B[k=(l>>4)*8+j][col=l&15],
//                            D[col=l&15][row=(l>>4)*4+reg]  (m89-verified).
// ---------------------------------------------------------------------------
#define ALD 520      // act leading dim (bf16 elems; 1040 B rows, 16B-aligned, 2-way banks)
#define XLD 40       // xt leading dim  (80 B rows)
#define SLD 68       // scratch leading dim (272 B rows, float4-aligned)

__global__ __launch_bounds__(512, 1) void k_vo(
    const float* __restrict__ x,
    const unsigned short* __restrict__ wv_hi, const unsigned short* __restrict__ wv_lo,
    const unsigned short* __restrict__ wo_hi, const unsigned short* __restrict__ wo_lo,
    const float* __restrict__ b_qkv, const float* __restrict__ b_out,
    const float* __restrict__ cv, float* __restrict__ out) {

    extern __shared__ char lds_raw[];
    unsigned short* act_hi = (unsigned short*)lds_raw;      // [64][ALD]
    unsigned short* act_lo = act_hi + 64 * ALD;
    unsigned short* xt_hi  = act_lo + 64 * ALD;             // [64][XLD]
    unsigned short* xt_lo  = xt_hi + 64 * XLD;
    float*          scratch = (float*)(xt_lo + 64 * XLD);   // [32][SLD]

    const int nt = blockIdx.x, bp = blockIdx.y;
    const int b = bp >> 2, p = bp & 3;
    const int n0 = nt * 64;
    const int tid = threadIdx.x;
    const int w  = tid >> 6;        // wave 0..7
    const int l  = tid & 63;
    const int lr = l & 15;          // frag row (A) / col (B,D)
    const int lg = l >> 4;          // k-group / D row-group

    const float* xb = x + (size_t)b * C * PN + (size_t)p * NN + n0;

    // staging index maps
    const int s_kk = tid >> 4, s_n4 = (tid & 15) * 4;       // scratch fill
    const int g_col = tid & 63, g_k4 = (tid >> 6) * 4;      // transpose gather

    // ---------------- Phase V: value = Wv @ x ----------------
    f32x4 acc[4][4];
    #pragma unroll
    for (int m = 0; m < 4; ++m)
        #pragma unroll
        for (int n = 0; n < 4; ++n) acc[m][n] = (f32x4){0.f, 0.f, 0.f, 0.f};

    for (int kt = 0; kt < 16; ++kt) {
        // 1) coalesced global -> scratch (fp32, natural [k][n])
        *reinterpret_cast<float4*>(&scratch[s_kk * SLD + s_n4]) =
            *reinterpret_cast<const float4*>(xb + (size_t)(kt * 32 + s_kk) * PN + s_n4);
        __syncthreads();
        // 2) transpose-gather + split -> xt[col][k] bf16 hi/lo
        {
            unsigned short h[4], lo[4];
            #pragma unroll
            for (int j = 0; j < 4; ++j) {
                const float v = scratch[(g_k4 + j) * SLD + g_col];
                h[j]  = bf16rne(v);
                lo[j] = bf16rne(v - bf16tof(h[j]));
            }
            uint2 ph, pl;
            ph.x = (unsigned)h[0]  | ((unsigned)h[1]  << 16);
            ph.y = (unsigned)h[2]  | ((unsigned)h[3]  << 16);
            pl.x = (unsigned)lo[0] | ((unsigned)lo[1] << 16);
            pl.y = (unsigned)lo[2] | ((unsigned)lo[3] << 16);
            *reinterpret_cast<uint2*>(&xt_hi[g_col * XLD + g_k4]) = ph;
            *reinterpret_cast<uint2*>(&xt_lo[g_col * XLD + g_k4]) = pl;
        }
        __syncthreads();
        // 3) one K-step (K=32) of MFMAs
        bf16x8 bh[4], bl[4];
        #pragma unroll
        for (int n = 0; n < 4; ++n) {
            bh[n] = *reinterpret_cast<const bf16x8*>(&xt_hi[(n * 16 + lr) * XLD + lg * 8]);
            bl[n] = *reinterpret_cast<const bf16x8*>(&xt_lo[(n * 16 + lr) * XLD + lg * 8]);
        }
        #pragma unroll
        for (int m = 0; m < 4; ++m) {
            const int row = w * 64 + m * 16 + lr;
            const bf16x8 ah = *reinterpret_cast<const bf16x8*>(&wv_hi[(size_t)row * C + kt * 32 + lg * 8]);
            const bf16x8 al = *reinterpret_cast<const bf16x8*>(&wv_lo[(size_t)row * C + kt * 32 + lg * 8]);
            #pragma unroll
            for (int n = 0; n < 4; ++n) {
                acc[m][n] = __builtin_amdgcn_mfma_f32_16x16x32_bf16(ah, bh[n], acc[m][n], 0, 0, 0);
                acc[m][n] = __builtin_amdgcn_mfma_f32_16x16x32_bf16(ah, bl[n], acc[m][n], 0, 0, 0);
                acc[m][n] = __builtin_amdgcn_mfma_f32_16x16x32_bf16(al, bh[n], acc[m][n], 0, 0, 0);
            }
        }
    }

    // finalize: act[col][c] = split(relu(value + b_v) * cv)
    {
        const float* bq  = b_qkv + 1 + C;
        const float* cvb = cv + bp * C;
        #pragma unroll
        for (int m = 0; m < 4; ++m) {
            const int r0 = w * 64 + m * 16 + lg * 4;
            float bias[4], cvv[4];
            #pragma unroll
            for (int j = 0; j < 4; ++j) { bias[j] = bq[r0 + j]; cvv[j] = cvb[r0 + j]; }
            #pragma unroll
            for (int n = 0; n < 4; ++n) {
                unsigned short hh[4], ll[4];
                #pragma unroll
                for (int j = 0; j < 4; ++j) {
                    const float av = fmaxf(acc[m][n][j] + bias[j], 0.f) * cvv[j];
                    hh[j] = bf16rne(av);
                    ll[j] = bf16rne(av - bf16tof(hh[j]));
                }
                uint2 ph, pl;
                ph.x = (unsigned)hh[0] | ((unsigned)hh[1] << 16);
                ph.y = (unsigned)hh[2] | ((unsigned)hh[3] << 16);
                pl.x = (unsigned)ll[0] | ((unsigned)ll[1] << 16);
                pl.y = (unsigned)ll[2] | ((unsigned)ll[3] << 16);
                *reinterpret_cast<uint2*>(&act_hi[(n * 16 + lr) * ALD + r0]) = ph;
                *reinterpret_cast<uint2*>(&act_lo[(n * 16 + lr) * ALD + r0]) = pl;
            }
        }
    }
    __syncthreads();

    // ---------------- Phase O: out = Wo @ act (barrier-free) ----------------
    f32x4 acc2[4][4];
    #pragma unroll
    for (int m = 0; m < 4; ++m)
        #pragma unroll
        for (int n = 0; n < 4; ++n) acc2[m][n] = (f32x4){0.f, 0.f, 0.f, 0.f};

    for (int kt = 0; kt < 16; ++kt) {
        bf16x8 bh[4], bl[4];
        #pragma unroll
        for (int n = 0; n < 4; ++n) {
            bh[n] = *reinterpret_cast<const bf16x8*>(&act_hi[(n * 16 + lr) * ALD + kt * 32 + lg * 8]);
            bl[n] = *reinterpret_cast<const bf16x8*>(&act_lo[(n * 16 + lr) * ALD + kt * 32 + lg * 8]);
        }
        #pragma unroll
        for (int m = 0; m < 4; ++m) {
            const int row = w * 64 + m * 16 + lr;
            const bf16x8 ah = *reinterpret_cast<const bf16x8*>(&wo_hi[(size_t)row * C + kt * 32 + lg * 8]);
            const bf16x8 al = *reinterpret_cast<const bf16x8*>(&wo_lo[(size_t)row * C + kt * 32 + lg * 8]);
            #pragma unroll
            for (int n = 0; n < 4; ++n) {
                acc2[m][n] = __builtin_amdgcn_mfma_f32_16x16x32_bf16(ah, bh[n], acc2[m][n], 0, 0, 0);
                acc2[m][n] = __builtin_amdgcn_mfma_f32_16x16x32_bf16(ah, bl[n], acc2[m][n], 0, 0, 0);
                acc2[m][n] = __builtin_amdgcn_mfma_f32_16x16x32_bf16(al, bh[n], acc2[m][n], 0, 0, 0);
            }
        }
    }

    // epilogue: out[b, o, p, n0+col] = acc2 + b_out
    #pragma unroll
    for (int m = 0; m < 4; ++m) {
        #pragma unroll
        for (int j = 0; j < 4; ++j) {
            const int row = w * 64 + m * 16 + lg * 4 + j;
            const float bo = b_out[row];
            float* orow = out + ((size_t)(b * C + row) * P + p) * NN + n0;
            #pragma unroll
            for (int n = 0; n < 4; ++n)
                orow[n * 16 + lr] = acc2[m][n][j] + bo;
        }
    }
}

// ---------------------------------------------------------------------------
extern "C" void kernel_launch(void* const* d_in, const int* in_sizes, int n_in,
                              void* d_out, int out_size, void* d_ws, size_t ws_size,
                              hipStream_t stream) {
    const float* x     = (const float*)d_in[0];
    const float* w_qkv = (const float*)d_in[1];
    const float* b_qkv = (const float*)d_in[2];
    const float* w_out = (const float*)d_in[3];
    const float* b_out = (const float*)d_in[4];
    float* out = (float*)d_out;

    float* query  = (float*)d_ws;            // BP*NN
    float* scores = query + BP * NN;         // BP*NN
    float* xs     = scores + BP * NN;        // BP*C
    float* cv     = xs + BP * C;             // BP*C
    unsigned short* wsp = (unsigned short*)(cv + BP * C);
    unsigned short* wv_hi = wsp;             // each [512*512] bf16
    unsigned short* wv_lo = wsp + C * C;
    unsigned short* wo_hi = wsp + 2 * C * C;
    unsigned short* wo_lo = wsp + 3 * C * C; // total ws ~2.9 MB

    k_split  <<<dim3(512),    256, 0, stream>>>(w_qkv, w_out, wv_hi, wv_lo, wo_hi, wo_lo);
    k_query  <<<dim3(BP * 4), 256, 0, stream>>>(x, w_qkv, b_qkv, query);
    k_softmax<<<dim3(BP),     256, 0, stream>>>(query, scores);
    k_xs     <<<dim3(BP * 8), 256, 0, stream>>>(x, scores, xs);
    k_cv     <<<dim3(BP),     256, 0, stream>>>(xs, w_qkv, b_qkv, cv);

    const size_t ldsbytes = (size_t)(2 * 64 * ALD + 2 * 64 * XLD) * 2 + (size_t)(32 * SLD) * 4;
    k_vo<<<dim3(16, BP), 512, ldsbytes, stream>>>(x, wv_hi, wv_lo, wo_hi, wo_lo,
                                                  b_qkv, b_out, cv, out);
}

// Round 4
// 624.476 us; speedup vs baseline: 2.4066x; 1.0394x over previous
//
#include <hip/hip_runtime.h>
#include <math.h>

// Shapes (fixed by the problem)
#define BB 16
#define C  512
#define P  4
#define NN 1024
#define BP (BB*P)     // 64
#define PN (P*NN)     // 4096 floats: stride between channels c for fixed (b,p)

typedef short bf16x8 __attribute__((ext_vector_type(8)));
typedef float f32x4  __attribute__((ext_vector_type(4)));
typedef unsigned short ushort_t;

__device__ __forceinline__ ushort_t bf16rne(float f) {
    unsigned u = __float_as_uint(f);
    u += 0x7FFFu + ((u >> 16) & 1u);
    return (ushort_t)(u >> 16);
}
__device__ __forceinline__ float bf16tof(ushort_t h) {
    return __uint_as_float(((unsigned)h) << 16);
}

// ---------------------------------------------------------------------------
// Kernel 0: split weights into bf16 hi/lo.  512 blocks x 256.
// ---------------------------------------------------------------------------
__global__ __launch_bounds__(256) void k_split(const float* __restrict__ w_qkv,
                                               const float* __restrict__ w_out,
                                               ushort_t* __restrict__ wv_hi,
                                               ushort_t* __restrict__ wv_lo,
                                               ushort_t* __restrict__ wo_hi,
                                               ushort_t* __restrict__ wo_lo) {
    const int i = blockIdx.x * 256 + threadIdx.x;   // 0..131071
    const int e = i * 4;
    const float* src; ushort_t *dh, *dl; int off;
    if (e < C * C) { src = w_qkv + (size_t)(1 + C) * C; dh = wv_hi; dl = wv_lo; off = e; }
    else           { src = w_out;                       dh = wo_hi; dl = wo_lo; off = e - C * C; }
    const float4 v = *reinterpret_cast<const float4*>(src + off);
    const float vv[4] = {v.x, v.y, v.z, v.w};
    ushort_t h[4], l[4];
    #pragma unroll
    for (int j = 0; j < 4; ++j) {
        h[j] = bf16rne(vv[j]);
        l[j] = bf16rne(vv[j] - bf16tof(h[j]));
    }
    uint2 ph, pl;
    ph.x = (unsigned)h[0] | ((unsigned)h[1] << 16);
    ph.y = (unsigned)h[2] | ((unsigned)h[3] << 16);
    pl.x = (unsigned)l[0] | ((unsigned)l[1] << 16);
    pl.y = (unsigned)l[2] | ((unsigned)l[3] << 16);
    *reinterpret_cast<uint2*>(dh + off) = ph;
    *reinterpret_cast<uint2*>(dl + off) = pl;
}

// ---------------------------------------------------------------------------
// Kernel 1: qpart[cc][bp][n] = sum_{c in chunk cc} w_q[c] * x[b,c,p,n]
// grid 512: (bp, cc of 8 x 64 channels). float4 over n, 8 indep chains.
// (b_q dropped: softmax is shift-invariant.)
// ---------------------------------------------------------------------------
__global__ __launch_bounds__(256) void k_query(const float* __restrict__ x,
                                               const float* __restrict__ w_qkv,
                                               float4* __restrict__ qpart4) {
    __shared__ float wq[64];
    const int bp = blockIdx.x >> 3, cc = blockIdx.x & 7;
    const int b = bp >> 2, p = bp & 3;
    const int tid = threadIdx.x;
    if (tid < 64) wq[tid] = w_qkv[cc * 64 + tid];
    __syncthreads();
    const float* xb = x + (size_t)b * C * PN + (size_t)p * NN;
    f32x4 acc[8];
    #pragma unroll
    for (int a = 0; a < 8; ++a) acc[a] = (f32x4){0.f, 0.f, 0.f, 0.f};
    #pragma unroll 8
    for (int i = 0; i < 64; ++i) {
        const float4 v = *reinterpret_cast<const float4*>(xb + (size_t)(cc * 64 + i) * PN + tid * 4);
        const float wv = wq[i];
        acc[i & 7][0] = fmaf(v.x, wv, acc[i & 7][0]);
        acc[i & 7][1] = fmaf(v.y, wv, acc[i & 7][1]);
        acc[i & 7][2] = fmaf(v.z, wv, acc[i & 7][2]);
        acc[i & 7][3] = fmaf(v.w, wv, acc[i & 7][3]);
    }
    f32x4 s = ((acc[0] + acc[1]) + (acc[2] + acc[3])) + ((acc[4] + acc[5]) + (acc[6] + acc[7]));
    float4 o; o.x = s[0]; o.y = s[1]; o.z = s[2]; o.w = s[3];
    qpart4[(cc * BP + bp) * 256 + tid] = o;
}

// ---------------------------------------------------------------------------
// Kernel 2: scores = softmax(sum_cc qpart) over N, per bp.  grid BP blocks.
// ---------------------------------------------------------------------------
__global__ __launch_bounds__(256) void k_softmax(const float4* __restrict__ qpart4,
                                                 float4* __restrict__ scores4) {
    __shared__ float red[256];
    const int bp = blockIdx.x, tid = threadIdx.x;
    float v[4] = {0.f, 0.f, 0.f, 0.f};
    #pragma unroll
    for (int cc = 0; cc < 8; ++cc) {
        const float4 q = qpart4[(cc * BP + bp) * 256 + tid];
        v[0] += q.x; v[1] += q.y; v[2] += q.z; v[3] += q.w;
    }
    float m = fmaxf(fmaxf(v[0], v[1]), fmaxf(v[2], v[3]));
    red[tid] = m; __syncthreads();
    for (int s = 128; s > 0; s >>= 1) {
        if (tid < s) red[tid] = fmaxf(red[tid], red[tid + s]);
        __syncthreads();
    }
    m = red[0]; __syncthreads();
    float sum = 0.f;
    #pragma unroll
    for (int j = 0; j < 4; ++j) { v[j] = expf(v[j] - m); sum += v[j]; }
    red[tid] = sum; __syncthreads();
    for (int s = 128; s > 0; s >>= 1) {
        if (tid < s) red[tid] += red[tid + s];
        __syncthreads();
    }
    const float inv = 1.0f / red[0];
    float4 o; o.x = v[0] * inv; o.y = v[1] * inv; o.z = v[2] * inv; o.w = v[3] * inv;
    scores4[bp * 256 + tid] = o;
}

// ---------------------------------------------------------------------------
// Kernel 3: xs[bp][c] = sum_n x[b,c,p,n] * scores[bp][n]
// grid 1024: (bp, cc of 16 x 32 channels). float4 loads, wave-per-8-rows.
// ---------------------------------------------------------------------------
__global__ __launch_bounds__(256) void k_xs(const float* __restrict__ x,
                                            const float4* __restrict__ scores4,
                                            float* __restrict__ xs) {
    __shared__ float4 sc4[256];
    const int bp = blockIdx.x >> 4, cc = blockIdx.x & 15;
    const int b = bp >> 2, p = bp & 3;
    const int tid = threadIdx.x;
    sc4[tid] = scores4[bp * 256 + tid];
    __syncthreads();
    const int wave = tid >> 6, lane = tid & 63;
    const float* xb = x + (size_t)b * C * PN + (size_t)p * NN;
    #pragma unroll
    for (int r = 0; r < 8; ++r) {
        const int c = cc * 32 + wave * 8 + r;
        const float4* row4 = reinterpret_cast<const float4*>(xb + (size_t)c * PN);
        float a0 = 0.f, a1 = 0.f, a2 = 0.f, a3 = 0.f;
        #pragma unroll
        for (int j = 0; j < 4; ++j) {
            const float4 xv = row4[lane + 64 * j];
            const float4 sv = sc4[lane + 64 * j];
            a0 = fmaf(xv.x, sv.x, a0);
            a1 = fmaf(xv.y, sv.y, a1);
            a2 = fmaf(xv.z, sv.z, a2);
            a3 = fmaf(xv.w, sv.w, a3);
        }
        float acc = (a0 + a1) + (a2 + a3);
        #pragma unroll
        for (int off = 32; off > 0; off >>= 1) acc += __shfl_down(acc, off);
        if (lane == 0) xs[bp * C + c] = acc;
    }
}

// ---------------------------------------------------------------------------
// Kernel 4: cv[bp][o] = b_qkv[1+o] + sum_c w_key[o][c] * xs[bp][c]
// ---------------------------------------------------------------------------
__global__ __launch_bounds__(256) void k_cv(const float* __restrict__ xs,
                                            const float* __restrict__ w_qkv,
                                            const float* __restrict__ b_qkv,
                                            float* __restrict__ cv) {
    __shared__ float xsl[C];
    const int bp = blockIdx.x, tid = threadIdx.x;
    for (int i = tid; i < C; i += 256) xsl[i] = xs[bp * C + i];
    __syncthreads();
    const int wave = tid >> 6, lane = tid & 63;
    for (int o = wave; o < C; o += 4) {
        const float* wr = w_qkv + (size_t)(1 + o) * C;
        float acc = 0.f;
        #pragma unroll
        for (int j = 0; j < 8; ++j) acc = fmaf(wr[lane + 64 * j], xsl[lane + 64 * j], acc);
        #pragma unroll
        for (int off = 32; off > 0; off >>= 1) acc += __shfl_down(acc, off);
        if (lane == 0) cv[bp * C + o] = acc + b_qkv[1 + o];
    }
}

// ---------------------------------------------------------------------------
// Kernel 5: MFMA bf16x3 fused value-GEMM -> relu*cv -> out-GEMM.
// Frag-linear LDS layouts (conflict-free ds_read_b128):
//   actf[dtype][kt(16)][n(4)][lane(64)][j(8)] : element = act[kt*32+(lane>>4)*8+j][n*16+(lane&15)]
//   xtf [buf(2)][dtype][n(4)][lane(64)][j(8)] : one K=32 slice of x, same map
// LDS: actf 128 KB + xtf 16 KB = 144 KB. 512 thr (8 waves), 1 block/CU.
// Phase V: 1 barrier/kt; next-kt x prefetched to regs before the 48 MFMAs.
// MFMA maps (16x16x32, m89-verified): A[row=l&15][k=(l>>4)*8+j],
//   B[k=(l>>4)*8+j][col=l&15], D[col=l&15][row=(l>>4)*4+reg].
// ---------------------------------------------------------------------------
#define XTFH 2048    // shorts per (buf,dtype): 4*64*8

__global__ __launch_bounds__(512, 1) void k_vo(
    const float* __restrict__ x,
    const ushort_t* __restrict__ wv_hi, const ushort_t* __restrict__ wv_lo,
    const ushort_t* __restrict__ wo_hi, const ushort_t* __restrict__ wo_lo,
    const float* __restrict__ b_qkv, const float* __restrict__ b_out,
    const float* __restrict__ cv, float* __restrict__ out) {

    extern __shared__ char lds_raw[];
    ushort_t* actf_hi = (ushort_t*)lds_raw;          // 32768 shorts
    ushort_t* actf_lo = actf_hi + 16 * 4 * 64 * 8;
    ushort_t* xtf     = actf_lo + 16 * 4 * 64 * 8;   // [2][2][XTFH]

    const int nt = blockIdx.x, bp = blockIdx.y;
    const int b = bp >> 2, p = bp & 3;
    const int n0 = nt * 64;
    const int tid = threadIdx.x;
    const int w  = tid >> 6;        // wave 0..7
    const int l  = tid & 63;
    const int lr = l & 15;
    const int lg = l >> 4;

    const float* xb = x + (size_t)b * C * PN + (size_t)p * NN + n0;

    // staging map: thread (g_col, g_k4) handles x[k = kt*32+g_k4+jj][col=g_col]
    const int g_col = tid & 63;
    const int g_k4  = (tid >> 6) * 4;                         // 0,4,...,28
    const int st_off = (((g_col >> 4) * 64 + (g_k4 >> 3) * 16 + (g_col & 15)) * 8) + (g_k4 & 7);

    // ---------------- Phase V: value = Wv @ x ----------------
    f32x4 acc[4][4];
    #pragma unroll
    for (int m = 0; m < 4; ++m)
        #pragma unroll
        for (int n = 0; n < 4; ++n) acc[m][n] = (f32x4){0.f, 0.f, 0.f, 0.f};

    // prologue: stage kt=0 into buffer 0
    {
        float xg[4];
        #pragma unroll
        for (int jj = 0; jj < 4; ++jj) xg[jj] = xb[(size_t)(g_k4 + jj) * PN + g_col];
        ushort_t h[4], lo[4];
        #pragma unroll
        for (int jj = 0; jj < 4; ++jj) {
            h[jj]  = bf16rne(xg[jj]);
            lo[jj] = bf16rne(xg[jj] - bf16tof(h[jj]));
        }
        uint2 ph, pl;
        ph.x = (unsigned)h[0]  | ((unsigned)h[1]  << 16);
        ph.y = (unsigned)h[2]  | ((unsigned)h[3]  << 16);
        pl.x = (unsigned)lo[0] | ((unsigned)lo[1] << 16);
        pl.y = (unsigned)lo[2] | ((unsigned)lo[3] << 16);
        *reinterpret_cast<uint2*>(&xtf[st_off])        = ph;
        *reinterpret_cast<uint2*>(&xtf[XTFH + st_off]) = pl;
    }
    __syncthreads();

    for (int kt = 0; kt < 16; ++kt) {
        const int cur = kt & 1;
        float xg[4];
        if (kt < 15) {   // prefetch next K-slice (in flight during MFMAs)
            #pragma unroll
            for (int jj = 0; jj < 4; ++jj)
                xg[jj] = xb[(size_t)((kt + 1) * 32 + g_k4 + jj) * PN + g_col];
        }
        const ushort_t* xh = xtf + cur * 2 * XTFH;
        const ushort_t* xl = xh + XTFH;
        bf16x8 bh[4], bl[4];
        #pragma unroll
        for (int n = 0; n < 4; ++n) {
            bh[n] = *reinterpret_cast<const bf16x8*>(&xh[(n * 64 + l) * 8]);
            bl[n] = *reinterpret_cast<const bf16x8*>(&xl[(n * 64 + l) * 8]);
        }
        #pragma unroll
        for (int m = 0; m < 4; ++m) {
            const int row = w * 64 + m * 16 + lr;
            const bf16x8 ah = *reinterpret_cast<const bf16x8*>(&wv_hi[(size_t)row * C + kt * 32 + lg * 8]);
            const bf16x8 al = *reinterpret_cast<const bf16x8*>(&wv_lo[(size_t)row * C + kt * 32 + lg * 8]);
            #pragma unroll
            for (int n = 0; n < 4; ++n) {
                acc[m][n] = __builtin_amdgcn_mfma_f32_16x16x32_bf16(ah, bh[n], acc[m][n], 0, 0, 0);
                acc[m][n] = __builtin_amdgcn_mfma_f32_16x16x32_bf16(ah, bl[n], acc[m][n], 0, 0, 0);
                acc[m][n] = __builtin_amdgcn_mfma_f32_16x16x32_bf16(al, bh[n], acc[m][n], 0, 0, 0);
            }
        }
        if (kt < 15) {   // convert + write next buffer
            ushort_t* dh = xtf + (cur ^ 1) * 2 * XTFH;
            ushort_t h[4], lo[4];
            #pragma unroll
            for (int jj = 0; jj < 4; ++jj) {
                h[jj]  = bf16rne(xg[jj]);
                lo[jj] = bf16rne(xg[jj] - bf16tof(h[jj]));
            }
            uint2 ph, pl;
            ph.x = (unsigned)h[0]  | ((unsigned)h[1]  << 16);
            ph.y = (unsigned)h[2]  | ((unsigned)h[3]  << 16);
            pl.x = (unsigned)lo[0] | ((unsigned)lo[1] << 16);
            pl.y = (unsigned)lo[2] | ((unsigned)lo[3] << 16);
            *reinterpret_cast<uint2*>(&dh[st_off])        = ph;
            *reinterpret_cast<uint2*>(&dh[XTFH + st_off]) = pl;
        }
        __syncthreads();
    }

    // finalize: actf[c][col] = split(relu(value + b_v) * cv), frag-linear
    {
        const float* bq  = b_qkv + 1 + C;
        const float* cvb = cv + bp * C;
        #pragma unroll
        for (int m = 0; m < 4; ++m) {
            const int rbase = w * 64 + m * 16 + lg * 4;      // + j, j=0..3
            const int ktp = w * 2 + (m >> 1);
            const int lgp = (m * 2 + (lg >> 1)) & 3;
            const int j0p = (lg & 1) * 4;
            float bias[4], cvv[4];
            #pragma unroll
            for (int j = 0; j < 4; ++j) { bias[j] = bq[rbase + j]; cvv[j] = cvb[rbase + j]; }
            #pragma unroll
            for (int n = 0; n < 4; ++n) {
                ushort_t hh[4], ll[4];
                #pragma unroll
                for (int j = 0; j < 4; ++j) {
                    const float av = fmaxf(acc[m][n][j] + bias[j], 0.f) * cvv[j];
                    hh[j] = bf16rne(av);
                    ll[j] = bf16rne(av - bf16tof(hh[j]));
                }
                uint2 ph, pl;
                ph.x = (unsigned)hh[0] | ((unsigned)hh[1] << 16);
                ph.y = (unsigned)hh[2] | ((unsigned)hh[3] << 16);
                pl.x = (unsigned)ll[0] | ((unsigned)ll[1] << 16);
                pl.y = (unsigned)ll[2] | ((unsigned)ll[3] << 16);
                const int off = ((ktp * 4 + n) * 64 + lgp * 16 + lr) * 8 + j0p;
                *reinterpret_cast<uint2*>(&actf_hi[off]) = ph;
                *reinterpret_cast<uint2*>(&actf_lo[off]) = pl;
            }
        }
    }
    __syncthreads();

    // ---------------- Phase O: out = Wo @ act (barrier-free) ----------------
    f32x4 acc2[4][4];
    #pragma unroll
    for (int m = 0; m < 4; ++m)
        #pragma unroll
        for (int n = 0; n < 4; ++n) acc2[m][n] = (f32x4){0.f, 0.f, 0.f, 0.f};

    for (int kt = 0; kt < 16; ++kt) {
        bf16x8 bh[4], bl[4];
        #pragma unroll
        for (int n = 0; n < 4; ++n) {
            bh[n] = *reinterpret_cast<const bf16x8*>(&actf_hi[((kt * 4 + n) * 64 + l) * 8]);
            bl[n] = *reinterpret_cast<const bf16x8*>(&actf_lo[((kt * 4 + n) * 64 + l) * 8]);
        }
        #pragma unroll
        for (int m = 0; m < 4; ++m) {
            const int row = w * 64 + m * 16 + lr;
            const bf16x8 ah = *reinterpret_cast<const bf16x8*>(&wo_hi[(size_t)row * C + kt * 32 + lg * 8]);
            const bf16x8 al = *reinterpret_cast<const bf16x8*>(&wo_lo[(size_t)row * C + kt * 32 + lg * 8]);
            #pragma unroll
            for (int n = 0; n < 4; ++n) {
                acc2[m][n] = __builtin_amdgcn_mfma_f32_16x16x32_bf16(ah, bh[n], acc2[m][n], 0, 0, 0);
                acc2[m][n] = __builtin_amdgcn_mfma_f32_16x16x32_bf16(ah, bl[n], acc2[m][n], 0, 0, 0);
                acc2[m][n] = __builtin_amdgcn_mfma_f32_16x16x32_bf16(al, bh[n], acc2[m][n], 0, 0, 0);
            }
        }
    }

    // epilogue: out[b, o, p, n0+col] = acc2 + b_out
    #pragma unroll
    for (int m = 0; m < 4; ++m) {
        #pragma unroll
        for (int j = 0; j < 4; ++j) {
            const int row = w * 64 + m * 16 + lg * 4 + j;
            const float bo = b_out[row];
            float* orow = out + ((size_t)(b * C + row) * P + p) * NN + n0;
            #pragma unroll
            for (int n = 0; n < 4; ++n)
                orow[n * 16 + lr] = acc2[m][n][j] + bo;
        }
    }
}

// ---------------------------------------------------------------------------
extern "C" void kernel_launch(void* const* d_in, const int* in_sizes, int n_in,
                              void* d_out, int out_size, void* d_ws, size_t ws_size,
                              hipStream_t stream) {
    const float* x     = (const float*)d_in[0];
    const float* w_qkv = (const float*)d_in[1];
    const float* b_qkv = (const float*)d_in[2];
    const float* w_out = (const float*)d_in[3];
    const float* b_out = (const float*)d_in[4];
    float* out = (float*)d_out;

    float* qpart  = (float*)d_ws;                    // 8*BP*NN   (2 MB)
    float* scores = qpart + 8 * BP * NN;             // BP*NN
    float* xs     = scores + BP * NN;                // BP*C
    float* cv     = xs + BP * C;                     // BP*C
    ushort_t* wsp = (ushort_t*)(cv + BP * C);
    ushort_t* wv_hi = wsp;                           // each C*C bf16 (512 KB)
    ushort_t* wv_lo = wsp + C * C;
    ushort_t* wo_hi = wsp + 2 * C * C;
    ushort_t* wo_lo = wsp + 3 * C * C;               // total ws ~4.5 MB

    k_split  <<<dim3(512),     256, 0, stream>>>(w_qkv, w_out, wv_hi, wv_lo, wo_hi, wo_lo);
    k_query  <<<dim3(BP * 8),  256, 0, stream>>>(x, w_qkv, (float4*)qpart);
    k_softmax<<<dim3(BP),      256, 0, stream>>>((const float4*)qpart, (float4*)scores);
    k_xs     <<<dim3(BP * 16), 256, 0, stream>>>(x, (const float4*)scores, xs);
    k_cv     <<<dim3(BP),      256, 0, stream>>>(xs, w_qkv, b_qkv, cv);

    const size_t ldsbytes = (size_t)(2 * 16 * 4 * 64 * 8 + 2 * 2 * XTFH) * sizeof(ushort_t); // 147456
    k_vo<<<dim3(16, BP), 512, ldsbytes, stream>>>(x, wv_hi, wv_lo, wo_hi, wo_lo,
                                                  b_qkv, b_out, cv, out);
}